// Round 3
// baseline (300.832 us; speedup 1.0000x reference)
//
#include <hip/hip_runtime.h>
#include <math.h>

#define BB 8
#define CC 128
#define HH 64
#define WW 64
#define NPTS 9
#define OUTC 256
#define HW (HH*WW)
#define KTOT (CC*NPTS)   // 1152
#define BK 288           // 32 channels * 9 taps per K-chunk
#define AP 296           // padded LDS row length in bf16 elems (148 words -> conflict-spread)

typedef __attribute__((ext_vector_type(8))) short bf16x8;
typedef __attribute__((ext_vector_type(4))) float f32x4;

__device__ __forceinline__ unsigned short f2bf(float f) {
    unsigned int u = __builtin_bit_cast(unsigned int, f);
    unsigned int r = (u + 0x7FFFu + ((u >> 16) & 1u)) >> 16;   // RNE
    return (unsigned short)r;
}

__device__ __forceinline__ bf16x8 loadw8(const float* p) {
    const float4* p4 = (const float4*)p;
    float4 lo = p4[0], hi = p4[1];
    bf16x8 r;
    r[0] = (short)f2bf(lo.x); r[1] = (short)f2bf(lo.y);
    r[2] = (short)f2bf(lo.z); r[3] = (short)f2bf(lo.w);
    r[4] = (short)f2bf(hi.x); r[5] = (short)f2bf(hi.y);
    r[6] = (short)f2bf(hi.z); r[7] = (short)f2bf(hi.w);
    return r;
}

// One block per (b, h): 256 threads = 4 waves. No global scratch (d_ws was the
// suspected post-timing-divergence source: 3.4 MB px/py/m may have overflowed
// ws_size and corrupted a neighboring input buffer -> replay drift).
__global__ __launch_bounds__(256, 2) void fused_kernel(
    const float* __restrict__ x,
    const float* __restrict__ w_offset, const float* __restrict__ b_offset,
    const float* __restrict__ w_mask,   const float* __restrict__ b_mask,
    const float* __restrict__ w_conv,
    const float* __restrict__ bn_gamma, const float* __restrict__ bn_beta,
    const float* __restrict__ bn_mean,  const float* __restrict__ bn_var,
    float* __restrict__ out)
{
    __shared__ unsigned short Atile[64][AP];          // 37.9 KB
    __shared__ float px_l[NPTS][64], py_l[NPTS][64], m_l[NPTS][64]; // 6.9 KB

    int blk = blockIdx.x;
    int b = blk >> 6, h = blk & 63;
    int tid  = threadIdx.x;
    int lane = tid & 63;
    int wv   = __builtin_amdgcn_readfirstlane(tid >> 6);  // wave 0..3
    int l15  = lane & 15;
    int kg   = lane >> 4;                                  // 0..3

    const float* xb = x + (size_t)b * CC * HW;

    // ================= stage 1: offset/mask conv (M=64,N=32,K=1152) ========
    // wave wv owns pixel rows [wv*16, wv*16+16); full K; N-frags {0..15},{16..31}
    f32x4 s1acc0 = {0.f, 0.f, 0.f, 0.f};
    f32x4 s1acc1 = {0.f, 0.f, 0.f, 0.f};

    for (int cb = 0; cb < 4; ++cb) {
        // -- build patch tile: A[pix][c_local*9 + ky*3+kx] = x[c][h+ky-1][pix+kx-1]
        {
            int pix = tid & 63;
            int cg  = tid >> 6;
            for (int i = 0; i < 8; ++i) {
                int c_local = cg * 8 + i;
                const float* xc = xb + (size_t)(cb * 32 + c_local) * HW;
                #pragma unroll
                for (int ky = 0; ky < 3; ++ky) {
                    int row = h + ky - 1;
                    bool rv = (row >= 0) & (row < HH);
                    #pragma unroll
                    for (int kx = 0; kx < 3; ++kx) {
                        int col = pix + kx - 1;
                        bool cv = rv & (col >= 0) & (col < WW);
                        float v = cv ? xc[row * WW + col] : 0.f;
                        Atile[pix][c_local * 9 + ky * 3 + kx] = f2bf(v);
                    }
                }
            }
        }
        __syncthreads();
        for (int q = 0; q < 9; ++q) {
            int koff  = q * 32 + kg * 8;
            int kglob = cb * BK + koff;
            bf16x8 af = *(const bf16x8*)&Atile[wv * 16 + l15][koff];
            // N-frag 0: cols 0..15 -> w_offset rows 0..15
            {
                bf16x8 bfr = loadw8(w_offset + (size_t)l15 * KTOT + kglob);
                s1acc0 = __builtin_amdgcn_mfma_f32_16x16x32_bf16(af, bfr, s1acc0, 0, 0, 0);
            }
            // N-frag 1: cols 16..31 -> 16,17: w_offset; 18..26: w_mask; 27+: zero
            {
                int nn = 16 + l15;
                const float* wp = (nn < 18)
                    ? (w_offset + (size_t)nn * KTOT + kglob)
                    : (w_mask + (size_t)(nn < 27 ? nn - 18 : 0) * KTOT + kglob);
                bf16x8 bfr = loadw8(wp);
                if (nn >= 27) {
                    #pragma unroll
                    for (int e = 0; e < 8; ++e) bfr[e] = 0;
                }
                s1acc1 = __builtin_amdgcn_mfma_f32_16x16x32_bf16(af, bfr, s1acc1, 0, 0, 0);
            }
        }
        __syncthreads();
    }

    // -- stage-1 epilogue: C[row=pix_local][col=nn], col=lane&15, row=kg*4+j
    #pragma unroll
    for (int f = 0; f < 2; ++f) {
        #pragma unroll
        for (int j = 0; j < 4; ++j) {
            float val = (f == 0) ? s1acc0[j] : s1acc1[j];
            int nn   = f * 16 + l15;
            int pixl = wv * 16 + kg * 4 + j;
            if (nn < 9) {
                px_l[nn][pixl] = val + b_offset[nn] + (float)(nn / 3 - 1) + (float)(h + 1);
            } else if (nn < 18) {
                int n = nn - 9;
                py_l[n][pixl] = val + b_offset[nn] + (float)(n % 3 - 1) + (float)(pixl + 1);
            } else if (nn < 27) {
                int n = nn - 18;
                float s = val + b_mask[n];
                m_l[n][pixl] = 1.f / (1.f + expf(-s));
            }
        }
    }
    __syncthreads();

    // ================= stage 2: bilinear params per thread (pix = tid&63) ===
    int spix = tid & 63;
    int scg  = tid >> 6;
    int   gidx[NPTS][4];
    float gw[NPTS][4];
    #pragma unroll
    for (int n = 0; n < NPTS; ++n) {
        float px = px_l[n][spix];
        float py = py_l[n][spix];
        float m  = m_l[n][spix];
        float fx = floorf(px), fy = floorf(py);
        float qltx = fminf(fmaxf(fx,       0.f), 65.f);
        float qlty = fminf(fmaxf(fy,       0.f), 65.f);
        float qrbx = fminf(fmaxf(fx + 1.f, 0.f), 65.f);
        float qrby = fminf(fmaxf(fy + 1.f, 0.f), 65.f);
        float pxc  = fminf(fmaxf(px, 0.f), 65.f);
        float pyc  = fminf(fmaxf(py, 0.f), 65.f);
        float glt = (1.f + (qltx - pxc)) * (1.f + (qlty - pyc)) * m;
        float grb = (1.f - (qrbx - pxc)) * (1.f - (qrby - pyc)) * m;
        float glb = (1.f + (qltx - pxc)) * (1.f - (qrby - pyc)) * m;
        float grt = (1.f - (qrbx - pxc)) * (1.f + (qlty - pyc)) * m;
        int i0 = (int)qltx - 1, j0 = (int)qlty - 1;
        int i1 = (int)qrbx - 1, j1 = (int)qrby - 1;
        bool v00 = (i0 >= 0) & (i0 < HH) & (j0 >= 0) & (j0 < WW);
        bool v11 = (i1 >= 0) & (i1 < HH) & (j1 >= 0) & (j1 < WW);
        bool v01 = (i0 >= 0) & (i0 < HH) & (j1 >= 0) & (j1 < WW);
        bool v10 = (i1 >= 0) & (i1 < HH) & (j0 >= 0) & (j0 < WW);
        gw[n][0] = v00 ? glt : 0.f;
        gw[n][1] = v11 ? grb : 0.f;
        gw[n][2] = v01 ? glb : 0.f;
        gw[n][3] = v10 ? grt : 0.f;
        gidx[n][0] = v00 ? (i0 * WW + j0) : 0;
        gidx[n][1] = v11 ? (i1 * WW + j1) : 0;
        gidx[n][2] = v01 ? (i0 * WW + j1) : 0;
        gidx[n][3] = v10 ? (i1 * WW + j0) : 0;
    }

    // ================= stage 2: main GEMM (M=64, N=256, K=1152) =============
    f32x4 acc[4][4];
    #pragma unroll
    for (int mi = 0; mi < 4; ++mi)
        #pragma unroll
        for (int ni = 0; ni < 4; ++ni)
            acc[mi][ni] = (f32x4){0.f, 0.f, 0.f, 0.f};

    int oc0 = wv * 64;

    for (int cb = 0; cb < 4; ++cb) {
        __syncthreads();   // prior MFMA reads of Atile complete before overwrite
        // -- build x_off tile: A[pix][c_local*9 + n]
        for (int i = 0; i < 8; ++i) {
            int c_local = scg * 8 + i;
            const float* xc = xb + (size_t)(cb * 32 + c_local) * HW;
            #pragma unroll
            for (int n = 0; n < NPTS; ++n) {
                float v =       gw[n][0] * xc[gidx[n][0]];
                v = fmaf(gw[n][1], xc[gidx[n][1]], v);
                v = fmaf(gw[n][2], xc[gidx[n][2]], v);
                v = fmaf(gw[n][3], xc[gidx[n][3]], v);
                Atile[spix][c_local * 9 + n] = f2bf(v);
            }
        }
        __syncthreads();
        for (int q = 0; q < 9; ++q) {
            int koff = q * 32 + kg * 8;
            bf16x8 af[4];
            #pragma unroll
            for (int mi = 0; mi < 4; ++mi)
                af[mi] = *(const bf16x8*)&Atile[mi * 16 + l15][koff];
            #pragma unroll
            for (int ni = 0; ni < 4; ++ni) {
                int oc = oc0 + ni * 16 + l15;
                bf16x8 bfr = loadw8(w_conv + (size_t)oc * KTOT + cb * BK + koff);
                #pragma unroll
                for (int mi = 0; mi < 4; ++mi)
                    acc[mi][ni] = __builtin_amdgcn_mfma_f32_16x16x32_bf16(af[mi], bfr, acc[mi][ni], 0, 0, 0);
            }
        }
    }

    // ================= epilogue: BN + ReLU, C[row=pix][col=oc] ==============
    #pragma unroll
    for (int ni = 0; ni < 4; ++ni) {
        int oc = oc0 + ni * 16 + l15;
        float inv   = 1.f / sqrtf(bn_var[oc] + 1e-5f);
        float scale = bn_gamma[oc] * inv;
        float shift = bn_beta[oc] - bn_mean[oc] * scale;
        float* op = out + ((size_t)b * OUTC + oc) * HW + h * WW;
        #pragma unroll
        for (int mi = 0; mi < 4; ++mi) {
            #pragma unroll
            for (int j = 0; j < 4; ++j) {
                int pix = mi * 16 + kg * 4 + j;
                float v = fmaf(acc[mi][ni][j], scale, shift);
                op[pix] = v > 0.f ? v : 0.f;
            }
        }
    }
}

extern "C" void kernel_launch(void* const* d_in, const int* in_sizes, int n_in,
                              void* d_out, int out_size, void* d_ws, size_t ws_size,
                              hipStream_t stream) {
    (void)in_sizes; (void)n_in; (void)out_size; (void)d_ws; (void)ws_size;
    const float* x        = (const float*)d_in[0];
    const float* w_offset = (const float*)d_in[1];
    const float* b_offset = (const float*)d_in[2];
    const float* w_mask   = (const float*)d_in[3];
    const float* b_mask   = (const float*)d_in[4];
    const float* w_conv   = (const float*)d_in[5];
    const float* bn_gamma = (const float*)d_in[6];
    const float* bn_beta  = (const float*)d_in[7];
    const float* bn_mean  = (const float*)d_in[8];
    const float* bn_var   = (const float*)d_in[9];
    float* out = (float*)d_out;

    fused_kernel<<<BB * HH, 256, 0, stream>>>(x, w_offset, b_offset, w_mask, b_mask,
                                              w_conv, bn_gamma, bn_beta, bn_mean, bn_var,
                                              out);
}

// Round 4
// 171.539 us; speedup vs baseline: 1.7537x; 1.7537x over previous
//
#include <hip/hip_runtime.h>
#include <math.h>

#define BB 8
#define CC 128
#define HH 64
#define WW 64
#define NPTS 9
#define OUTC 256
#define HW (HH*WW)
#define KTOT (CC*NPTS)   // 1152
#define BK 288           // 32 channels * 9 taps per K-chunk
#define AP 296           // padded Atile row (bf16 elems); 148 words spreads banks
#define WROWS 6          // x row window: global rows h-2 .. h+3

typedef __attribute__((ext_vector_type(8))) short bf16x8;
typedef __attribute__((ext_vector_type(4))) float f32x4;

__device__ __forceinline__ unsigned short f2bf(float f) {
    unsigned int u = __builtin_bit_cast(unsigned int, f);
    unsigned int r = (u + 0x7FFFu + ((u >> 16) & 1u)) >> 16;   // RNE
    return (unsigned short)r;
}

__device__ __forceinline__ bf16x8 loadw8(const float* p) {
    const float4* p4 = (const float4*)p;
    float4 lo = p4[0], hi = p4[1];
    bf16x8 r;
    r[0] = (short)f2bf(lo.x); r[1] = (short)f2bf(lo.y);
    r[2] = (short)f2bf(lo.z); r[3] = (short)f2bf(lo.w);
    r[4] = (short)f2bf(hi.x); r[5] = (short)f2bf(hi.y);
    r[6] = (short)f2bf(hi.z); r[7] = (short)f2bf(hi.w);
    return r;
}

// Stage 8 channels x 6 rows x 64 cols of x (f32) into LDS window.
// Rows outside [0,63] -> zeros (matches conv zero-pad / zero-weight corners).
__device__ __forceinline__ void stage_win(float win[8][WROWS*WW],
                                          const float* __restrict__ xb,
                                          int h, int cb, int s, int tid) {
    int c8 = tid >> 5, sub = tid & 31;
    const float* xc = xb + (size_t)(cb * 32 + s * 8 + c8) * HW;
    #pragma unroll
    for (int t = 0; t < 3; ++t) {
        int e0 = (sub + 32 * t) * 4;            // 0..380, multiple of 4
        int r = e0 >> 6, col = e0 & 63;
        int gr = h - 2 + r;
        float4 v = make_float4(0.f, 0.f, 0.f, 0.f);
        if (gr >= 0 && gr < HH) v = *(const float4*)(xc + gr * WW + col);
        *(float4*)&win[c8][e0] = v;
    }
}

__global__ __launch_bounds__(256, 2) void fused_kernel(
    const float* __restrict__ x,
    const float* __restrict__ w_offset, const float* __restrict__ b_offset,
    const float* __restrict__ w_mask,   const float* __restrict__ b_mask,
    const float* __restrict__ w_conv,
    const float* __restrict__ bn_gamma, const float* __restrict__ bn_beta,
    const float* __restrict__ bn_mean,  const float* __restrict__ bn_var,
    float* __restrict__ out)
{
    __shared__ unsigned short Atile[64][AP];                    // 37.9 KB
    __shared__ float win[8][WROWS * WW];                        // 12 KB
    __shared__ float px_l[NPTS][64], py_l[NPTS][64], m_l[NPTS][64]; // 6.9 KB

    int blk = blockIdx.x;
    int b = blk >> 6, h = blk & 63;
    int tid  = threadIdx.x;
    int lane = tid & 63;
    int wv   = __builtin_amdgcn_readfirstlane(tid >> 6);  // wave 0..3
    int l15  = lane & 15;
    int kg   = lane >> 4;
    int spix = lane;                                      // pixel for build phases

    const float* xb = x + (size_t)b * CC * HW;

    // ================= PASS A: offset/mask conv (M=64,N=32,K=1152) =========
    f32x4 s1acc0 = {0.f, 0.f, 0.f, 0.f};
    f32x4 s1acc1 = {0.f, 0.f, 0.f, 0.f};

    for (int cb = 0; cb < 4; ++cb) {
        for (int s = 0; s < 4; ++s) {
            __syncthreads();                 // win free (and Atile free at s==0)
            stage_win(win, xb, h, cb, s, tid);
            __syncthreads();                 // win ready
            #pragma unroll
            for (int ci = 0; ci < 2; ++ci) {
                int wc  = wv * 2 + ci;       // channel within window
                int c32 = s * 8 + wc;        // channel within cb
                const float* wrow = &win[wc][0];
                #pragma unroll
                for (int ky = 0; ky < 3; ++ky) {
                    #pragma unroll
                    for (int kx = 0; kx < 3; ++kx) {
                        int col  = spix + kx - 1;
                        int colc = min(max(col, 0), WW - 1);
                        float v = wrow[(ky + 1) * WW + colc];  // row h+ky-1
                        v = (col >= 0 && col < WW) ? v : 0.f;
                        Atile[spix][c32 * 9 + ky * 3 + kx] = f2bf(v);
                    }
                }
            }
        }
        __syncthreads();                     // Atile complete
        for (int q = 0; q < 9; ++q) {
            int koff  = q * 32 + kg * 8;
            int kglob = cb * BK + koff;
            bf16x8 af = *(const bf16x8*)&Atile[wv * 16 + l15][koff];
            {   // N-frag 0: cols 0..15 of w_offset
                bf16x8 bfr = loadw8(w_offset + (size_t)l15 * KTOT + kglob);
                s1acc0 = __builtin_amdgcn_mfma_f32_16x16x32_bf16(af, bfr, s1acc0, 0, 0, 0);
            }
            {   // N-frag 1: 16,17 w_offset; 18..26 w_mask; 27+ zero
                int nn = 16 + l15;
                const float* wp = (nn < 18)
                    ? (w_offset + (size_t)nn * KTOT + kglob)
                    : (w_mask + (size_t)(nn < 27 ? nn - 18 : 0) * KTOT + kglob);
                bf16x8 bfr = loadw8(wp);
                if (nn >= 27) {
                    #pragma unroll
                    for (int e = 0; e < 8; ++e) bfr[e] = 0;
                }
                s1acc1 = __builtin_amdgcn_mfma_f32_16x16x32_bf16(af, bfr, s1acc1, 0, 0, 0);
            }
        }
    }

    // ---- pass-A epilogue: C[row=pix][col=nn]; col=lane&15, row=kg*4+j ----
    #pragma unroll
    for (int f = 0; f < 2; ++f) {
        #pragma unroll
        for (int j = 0; j < 4; ++j) {
            float val = (f == 0) ? s1acc0[j] : s1acc1[j];
            int nn   = f * 16 + l15;
            int pixl = wv * 16 + kg * 4 + j;
            if (nn < 9) {
                px_l[nn][pixl] = val + b_offset[nn] + (float)(nn / 3 - 1) + (float)(h + 1);
            } else if (nn < 18) {
                int n = nn - 9;
                py_l[n][pixl] = val + b_offset[nn] + (float)(n % 3 - 1) + (float)(pixl + 1);
            } else if (nn < 27) {
                int n = nn - 18;
                float sg = val + b_mask[n];
                m_l[n][pixl] = 1.f / (1.f + expf(-sg));
            }
        }
    }
    __syncthreads();

    // ================= per-thread bilinear params (pixel = spix) ============
    float gw[NPTS][4];
    int off00[NPTS], drr[NPTS], djj[NPTS];
    unsigned okmask = 0;
    #pragma unroll
    for (int n = 0; n < NPTS; ++n) {
        float px = px_l[n][spix];
        float py = py_l[n][spix];
        float m  = m_l[n][spix];
        float fx = floorf(px), fy = floorf(py);
        float qltx = fminf(fmaxf(fx,       0.f), 65.f);
        float qlty = fminf(fmaxf(fy,       0.f), 65.f);
        float qrbx = fminf(fmaxf(fx + 1.f, 0.f), 65.f);
        float qrby = fminf(fmaxf(fy + 1.f, 0.f), 65.f);
        float pxc  = fminf(fmaxf(px, 0.f), 65.f);
        float pyc  = fminf(fmaxf(py, 0.f), 65.f);
        float glt = (1.f + (qltx - pxc)) * (1.f + (qlty - pyc)) * m;
        float grb = (1.f - (qrbx - pxc)) * (1.f - (qrby - pyc)) * m;
        float glb = (1.f + (qltx - pxc)) * (1.f - (qrby - pyc)) * m;
        float grt = (1.f - (qrbx - pxc)) * (1.f + (qlty - pyc)) * m;
        int i0 = (int)qltx - 1, j0 = (int)qlty - 1;
        int i1 = (int)qrbx - 1, j1 = (int)qrby - 1;
        bool v00 = (i0 >= 0) & (i0 < HH) & (j0 >= 0) & (j0 < WW);
        bool v11 = (i1 >= 0) & (i1 < HH) & (j1 >= 0) & (j1 < WW);
        bool v01 = (i0 >= 0) & (i0 < HH) & (j1 >= 0) & (j1 < WW);
        bool v10 = (i1 >= 0) & (i1 < HH) & (j0 >= 0) & (j0 < WW);
        gw[n][0] = v00 ? glt : 0.f;   // (i0,j0)
        gw[n][1] = v11 ? grb : 0.f;   // (i1,j1)
        gw[n][2] = v01 ? glb : 0.f;   // (i0,j1)
        gw[n][3] = v10 ? grt : 0.f;   // (i1,j0)
        // rows-in-window check: only corners with nonzero weight matter
        bool okr0 = ((i0 >= h - 2) & (i0 <= h + 3)) | !(v00 | v01);
        bool okr1 = ((i1 >= h - 2) & (i1 <= h + 3)) | !(v11 | v10);
        if (okr0 & okr1) okmask |= (1u << n);
        int r0  = min(max(i0 - (h - 2), 0), WROWS - 1);
        int r1  = min(max(i1 - (h - 2), 0), WROWS - 1);
        int j0c = min(max(j0, 0), WW - 1);
        int j1c = min(max(j1, 0), WW - 1);
        off00[n] = r0 * WW + j0c;
        drr[n]   = (r1 - r0) * WW;
        djj[n]   = j1c - j0c;
    }

    // ================= PASS B: main GEMM (M=64, N=256, K=1152) ==============
    f32x4 acc[4][4];
    #pragma unroll
    for (int mi = 0; mi < 4; ++mi)
        #pragma unroll
        for (int ni = 0; ni < 4; ++ni)
            acc[mi][ni] = (f32x4){0.f, 0.f, 0.f, 0.f};

    int oc0 = wv * 64;

    for (int cb = 0; cb < 4; ++cb) {
        for (int s = 0; s < 4; ++s) {
            __syncthreads();                 // win free; Atile free at s==0
            stage_win(win, xb, h, cb, s, tid);
            __syncthreads();                 // win ready
            #pragma unroll
            for (int ci = 0; ci < 2; ++ci) {
                int wc  = wv * 2 + ci;
                int c32 = s * 8 + wc;
                const float* winc = &win[wc][0];
                #pragma unroll
                for (int n = 0; n < NPTS; ++n) {
                    int o = off00[n];
                    float x00 = winc[o];
                    float x01 = winc[o + djj[n]];
                    float x10 = winc[o + drr[n]];
                    float x11 = winc[o + drr[n] + djj[n]];
                    float v =       gw[n][0] * x00;
                    v = fmaf(gw[n][1], x11, v);
                    v = fmaf(gw[n][2], x01, v);
                    v = fmaf(gw[n][3], x10, v);
                    Atile[spix][c32 * 9 + n] = f2bf(v);
                }
            }
            // rare fallback: offset pushed a corner outside the 6-row window
            if (__builtin_expect(okmask != 0x1ffu, 0)) {
                #pragma unroll 1
                for (int n = 0; n < NPTS; ++n) {
                    if ((okmask >> n) & 1u) continue;
                    float px = px_l[n][spix];
                    float py = py_l[n][spix];
                    float m  = m_l[n][spix];
                    float fx = floorf(px), fy = floorf(py);
                    float qltx = fminf(fmaxf(fx,       0.f), 65.f);
                    float qlty = fminf(fmaxf(fy,       0.f), 65.f);
                    float qrbx = fminf(fmaxf(fx + 1.f, 0.f), 65.f);
                    float qrby = fminf(fmaxf(fy + 1.f, 0.f), 65.f);
                    float pxc  = fminf(fmaxf(px, 0.f), 65.f);
                    float pyc  = fminf(fmaxf(py, 0.f), 65.f);
                    float glt = (1.f + (qltx - pxc)) * (1.f + (qlty - pyc)) * m;
                    float grb = (1.f - (qrbx - pxc)) * (1.f - (qrby - pyc)) * m;
                    float glb = (1.f + (qltx - pxc)) * (1.f - (qrby - pyc)) * m;
                    float grt = (1.f - (qrbx - pxc)) * (1.f + (qlty - pyc)) * m;
                    int i0 = (int)qltx - 1, j0 = (int)qlty - 1;
                    int i1 = (int)qrbx - 1, j1 = (int)qrby - 1;
                    bool v00 = (i0 >= 0) & (i0 < HH) & (j0 >= 0) & (j0 < WW);
                    bool v11 = (i1 >= 0) & (i1 < HH) & (j1 >= 0) & (j1 < WW);
                    bool v01 = (i0 >= 0) & (i0 < HH) & (j1 >= 0) & (j1 < WW);
                    bool v10 = (i1 >= 0) & (i1 < HH) & (j0 >= 0) & (j0 < WW);
                    float w0 = v00 ? glt : 0.f, w1 = v11 ? grb : 0.f;
                    float w2 = v01 ? glb : 0.f, w3 = v10 ? grt : 0.f;
                    int g0 = v00 ? (i0 * WW + j0) : 0;
                    int g1 = v11 ? (i1 * WW + j1) : 0;
                    int g2 = v01 ? (i0 * WW + j1) : 0;
                    int g3 = v10 ? (i1 * WW + j0) : 0;
                    #pragma unroll
                    for (int ci = 0; ci < 2; ++ci) {
                        int c32 = s * 8 + wv * 2 + ci;
                        const float* xc = xb + (size_t)(cb * 32 + c32) * HW;
                        float v =       w0 * xc[g0];
                        v = fmaf(w1, xc[g1], v);
                        v = fmaf(w2, xc[g2], v);
                        v = fmaf(w3, xc[g3], v);
                        Atile[spix][c32 * 9 + n] = f2bf(v);
                    }
                }
            }
        }
        __syncthreads();                     // Atile complete
        for (int q = 0; q < 9; ++q) {
            int koff = q * 32 + kg * 8;
            bf16x8 af[4];
            #pragma unroll
            for (int mi = 0; mi < 4; ++mi)
                af[mi] = *(const bf16x8*)&Atile[mi * 16 + l15][koff];
            #pragma unroll
            for (int ni = 0; ni < 4; ++ni) {
                int oc = oc0 + ni * 16 + l15;
                bf16x8 bfr = loadw8(w_conv + (size_t)oc * KTOT + cb * BK + koff);
                #pragma unroll
                for (int mi = 0; mi < 4; ++mi)
                    acc[mi][ni] = __builtin_amdgcn_mfma_f32_16x16x32_bf16(af[mi], bfr, acc[mi][ni], 0, 0, 0);
            }
        }
    }

    // ================= epilogue: BN + ReLU, float4 stores ===================
    #pragma unroll
    for (int ni = 0; ni < 4; ++ni) {
        int oc = oc0 + ni * 16 + l15;
        float inv   = 1.f / sqrtf(bn_var[oc] + 1e-5f);
        float scale = bn_gamma[oc] * inv;
        float shift = bn_beta[oc] - bn_mean[oc] * scale;
        float* op = out + ((size_t)b * OUTC + oc) * HW + h * WW + kg * 4;
        #pragma unroll
        for (int mi = 0; mi < 4; ++mi) {
            f32x4 o4;
            #pragma unroll
            for (int j = 0; j < 4; ++j) {
                float v = fmaf(acc[mi][ni][j], scale, shift);
                o4[j] = v > 0.f ? v : 0.f;
            }
            *(f32x4*)(op + mi * 16) = o4;
        }
    }
}

extern "C" void kernel_launch(void* const* d_in, const int* in_sizes, int n_in,
                              void* d_out, int out_size, void* d_ws, size_t ws_size,
                              hipStream_t stream) {
    (void)in_sizes; (void)n_in; (void)out_size; (void)d_ws; (void)ws_size;
    const float* x        = (const float*)d_in[0];
    const float* w_offset = (const float*)d_in[1];
    const float* b_offset = (const float*)d_in[2];
    const float* w_mask   = (const float*)d_in[3];
    const float* b_mask   = (const float*)d_in[4];
    const float* w_conv   = (const float*)d_in[5];
    const float* bn_gamma = (const float*)d_in[6];
    const float* bn_beta  = (const float*)d_in[7];
    const float* bn_mean  = (const float*)d_in[8];
    const float* bn_var   = (const float*)d_in[9];
    float* out = (float*)d_out;

    fused_kernel<<<BB * HH, 256, 0, stream>>>(x, w_offset, b_offset, w_mask, b_mask,
                                              w_conv, bn_gamma, bn_beta, bn_mean, bn_var,
                                              out);
}